// Round 15
// baseline (304.506 us; speedup 1.0000x reference)
//
#include <hip/hip_runtime.h>

#define DF 128
#define CAP 40    // max in-degree bucket capacity; in-deg ~ Poisson(12), realized max ~30

// NOTE: parameter names must not collide with float4 member names (x,y,z,w):
// macro substitution rewrites identifiers even after '.', so a param named
// 'w' would turn 'v.w' into 'v.<arg>'.
#define FMA4(a4, s, v)                                              \
    a4.x = fmaf(s, v.x, a4.x); a4.y = fmaf(s, v.y, a4.y);           \
    a4.z = fmaf(s, v.z, a4.z); a4.w = fmaf(s, v.w, a4.w)

// ---------------------------------------------------------------------------
// MEASURED HISTORY (do not re-try without new evidence):
//  - 4-edge-per-thread build: REGRESSION (R4 83.6 -> R8 91.8us). 1 edge/thr.
//  - agg4 (4-node interleave): REGRESSION vs agg2. Keep agg2.
//  - agg2 (2-node interleave): WIN (agg_gemm 108 -> <83.6us).
//  - h2 pre-scale (SCALE_OUT epilogue): WIN component of R10 best (281.6us).
//  - direct-X gemm1 (R11): REGRESSION (global broadcast loads stall).
//  - split build/gemm1 + h1 pre-scale (R14): REGRESSION 304.3 (+23us =
//    lost overlap ~11 + extra launch gap ~12; SCALED agg won only ~3).
//    DECISIVE: build standalone at high occupancy is still ~75-80us ->
//    build is atomic/fabric-throughput-bound; occupancy/MLP levers dead.
//  - R15 experiment: agg_gemm tile 32->64 rows (halve Wsk stagings,
//    barriers, W2 re-fetch per output row).
// ---------------------------------------------------------------------------

// ---------------------------------------------------------------------------
// 4-way-unrolled tail aggregation starting at record i:
//   SCALED=false: acc += sum w_i * rsqrt(deg[src_i]) * H[src_i][4t..4t+3]
//   SCALED=true:  acc += sum w_i * H[src_i][...]   (H rows pre-scaled)
// bucket is 16B-aligned (csr base 512B-aligned, node*CAP*8 = node*320).
// ---------------------------------------------------------------------------
template <bool SCALED>
__device__ __forceinline__ float4 agg_tail(const float4* __restrict__ H4,
                                           const int2* __restrict__ bucket,
                                           int i, int m,
                                           const float* __restrict__ deg,
                                           int t, float4 acc)
{
    for (; i + 4 <= m; i += 4) {
        const int4* b4 = (const int4*)(bucket + i);
        const int4 p0 = b4[0];
        const int4 p1 = b4[1];
        const float4 h0 = H4[(size_t)p0.x * 32 + t];
        const float4 h1 = H4[(size_t)p0.z * 32 + t];
        const float4 h2 = H4[(size_t)p1.x * 32 + t];
        const float4 h3 = H4[(size_t)p1.z * 32 + t];
        const float s0 = SCALED ? __int_as_float(p0.y) : __int_as_float(p0.y) * rsqrtf(deg[p0.x]);
        const float s1 = SCALED ? __int_as_float(p0.w) : __int_as_float(p0.w) * rsqrtf(deg[p0.z]);
        const float s2 = SCALED ? __int_as_float(p1.y) : __int_as_float(p1.y) * rsqrtf(deg[p1.x]);
        const float s3 = SCALED ? __int_as_float(p1.w) : __int_as_float(p1.w) * rsqrtf(deg[p1.z]);
        FMA4(acc, s0, h0);
        FMA4(acc, s1, h1);
        FMA4(acc, s2, h2);
        FMA4(acc, s3, h3);
    }
    for (; i < m; ++i) {
        const int2 rec = bucket[i];
        const float sv = SCALED ? __int_as_float(rec.y) : __int_as_float(rec.y) * rsqrtf(deg[rec.x]);
        const float4 hv = H4[(size_t)rec.x * 32 + t];
        FMA4(acc, sv, hv);
    }
    return acc;
}

// ---------------------------------------------------------------------------
// Two-node interleaved aggregation: 8 independent 512B gathers in flight per
// iteration over the common prefix, then per-node tails. Summation order
// within each node is unchanged.
// ---------------------------------------------------------------------------
template <bool SCALED>
__device__ __forceinline__ void agg2(const float4* __restrict__ H4,
                                     const int2* __restrict__ bA, int mA,
                                     const int2* __restrict__ bB, int mB,
                                     const float* __restrict__ deg, int t,
                                     float4& accA, float4& accB)
{
    const int mc = mA < mB ? mA : mB;
    int i = 0;
    for (; i + 4 <= mc; i += 4) {
        const int4 a0 = ((const int4*)(bA + i))[0];
        const int4 a1 = ((const int4*)(bA + i))[1];
        const int4 c0 = ((const int4*)(bB + i))[0];
        const int4 c1 = ((const int4*)(bB + i))[1];
        const float4 hA0 = H4[(size_t)a0.x * 32 + t];
        const float4 hA1 = H4[(size_t)a0.z * 32 + t];
        const float4 hA2 = H4[(size_t)a1.x * 32 + t];
        const float4 hA3 = H4[(size_t)a1.z * 32 + t];
        const float4 hB0 = H4[(size_t)c0.x * 32 + t];
        const float4 hB1 = H4[(size_t)c0.z * 32 + t];
        const float4 hB2 = H4[(size_t)c1.x * 32 + t];
        const float4 hB3 = H4[(size_t)c1.z * 32 + t];
        const float sA0 = SCALED ? __int_as_float(a0.y) : __int_as_float(a0.y) * rsqrtf(deg[a0.x]);
        const float sA1 = SCALED ? __int_as_float(a0.w) : __int_as_float(a0.w) * rsqrtf(deg[a0.z]);
        const float sA2 = SCALED ? __int_as_float(a1.y) : __int_as_float(a1.y) * rsqrtf(deg[a1.x]);
        const float sA3 = SCALED ? __int_as_float(a1.w) : __int_as_float(a1.w) * rsqrtf(deg[a1.z]);
        const float sB0 = SCALED ? __int_as_float(c0.y) : __int_as_float(c0.y) * rsqrtf(deg[c0.x]);
        const float sB1 = SCALED ? __int_as_float(c0.w) : __int_as_float(c0.w) * rsqrtf(deg[c0.z]);
        const float sB2 = SCALED ? __int_as_float(c1.y) : __int_as_float(c1.y) * rsqrtf(deg[c1.x]);
        const float sB3 = SCALED ? __int_as_float(c1.w) : __int_as_float(c1.w) * rsqrtf(deg[c1.z]);
        FMA4(accA, sA0, hA0);
        FMA4(accA, sA1, hA1);
        FMA4(accA, sA2, hA2);
        FMA4(accA, sA3, hA3);
        FMA4(accB, sB0, hB0);
        FMA4(accB, sB1, hB1);
        FMA4(accB, sB2, hB2);
        FMA4(accB, sB3, hB3);
    }
    accA = agg_tail<SCALED>(H4, bA, i, mA, deg, t, accA);
    accB = agg_tail<SCALED>(H4, bB, i, mB, deg, t, accB);
}

// ---------------------------------------------------------------------------
// Register-blocked GEMM core: H[n0 : n0+8*RPT] = Xs @ W^T + b.
// RPT = rows per thread (= rows per 32-lane group). Xs is (8*RPT) x 128
// row-major in LDS, fully populated by the caller (first __syncthreads in
// the k0 loop fences it). Wsk is a 32 x 128 k-slice of W, transposed.
// SCALE_OUT: multiply output row n by rsqrt(degv[n]) before the store.
// ---------------------------------------------------------------------------
template <int RPT, bool SCALE_OUT>
__device__ __forceinline__ void gemm_from_lds(
    float* __restrict__ Xs, float* __restrict__ Wsk,
    const float* __restrict__ W, const float* __restrict__ b,
    float* __restrict__ H, int nrows, int n0, int tid,
    const float* __restrict__ degv)
{
    const int rgrp = tid >> 5;
    const int cgrp = tid & 31;

    float4 acc[RPT];
    const float4 bias = ((const float4*)b)[cgrp];
#pragma unroll
    for (int r = 0; r < RPT; ++r) acc[r] = bias;

    const float4* Xs4 = (const float4*)Xs;
    const float4* Ws4 = (const float4*)Wsk;

    for (int k0 = 0; k0 < DF; k0 += 32) {
        __syncthreads();
#pragma unroll
        for (int i = 0; i < 4; ++i) {
            int idx = tid + i * 256;
            int c   = idx >> 3;
            int kk  = idx & 7;
            float4 v = ((const float4*)(W + (size_t)c * DF + k0))[kk];
            int kb = kk * 4;
            Wsk[(kb + 0) * DF + c] = v.x;
            Wsk[(kb + 1) * DF + c] = v.y;
            Wsk[(kb + 2) * DF + c] = v.z;
            Wsk[(kb + 3) * DF + c] = v.w;
        }
        __syncthreads();

#pragma unroll
        for (int kk = 0; kk < 8; ++kk) {
            const int kb = (k0 >> 2) + kk;
            float4 w0 = Ws4[(kk * 4 + 0) * 32 + cgrp];
            float4 w1 = Ws4[(kk * 4 + 1) * 32 + cgrp];
            float4 w2 = Ws4[(kk * 4 + 2) * 32 + cgrp];
            float4 w3 = Ws4[(kk * 4 + 3) * 32 + cgrp];
#pragma unroll
            for (int r = 0; r < RPT; ++r) {
                float4 x4 = Xs4[(rgrp * RPT + r) * 32 + kb];
                acc[r].x = fmaf(x4.x, w0.x, acc[r].x);
                acc[r].y = fmaf(x4.x, w0.y, acc[r].y);
                acc[r].z = fmaf(x4.x, w0.z, acc[r].z);
                acc[r].w = fmaf(x4.x, w0.w, acc[r].w);
                acc[r].x = fmaf(x4.y, w1.x, acc[r].x);
                acc[r].y = fmaf(x4.y, w1.y, acc[r].y);
                acc[r].z = fmaf(x4.y, w1.z, acc[r].z);
                acc[r].w = fmaf(x4.y, w1.w, acc[r].w);
                acc[r].x = fmaf(x4.z, w2.x, acc[r].x);
                acc[r].y = fmaf(x4.z, w2.y, acc[r].y);
                acc[r].z = fmaf(x4.z, w2.z, acc[r].z);
                acc[r].w = fmaf(x4.z, w2.w, acc[r].w);
                acc[r].x = fmaf(x4.w, w3.x, acc[r].x);
                acc[r].y = fmaf(x4.w, w3.y, acc[r].y);
                acc[r].z = fmaf(x4.w, w3.z, acc[r].z);
                acc[r].w = fmaf(x4.w, w3.w, acc[r].w);
            }
        }
    }

#pragma unroll
    for (int r = 0; r < RPT; ++r) {
        int n = n0 + rgrp * RPT + r;
        if (n < nrows) {
            if (SCALE_OUT) {
                const float d = rsqrtf(degv[n]);
                acc[r].x *= d; acc[r].y *= d; acc[r].z *= d; acc[r].w *= d;
            }
            ((float4*)(H + (size_t)n * DF))[cgrp] = acc[r];
        }
    }
}

// ==== fused: blocks [0,gemmBlocks) = GEMM1 64-row tile; rest = CSR build ====
// 64-row tile + 1-edge-per-thread build: R10-measured best (281.6us total,
// this kernel 84us). Build is fabric-bound (R14) — keep fused for overlap.
__global__ __launch_bounds__(256) void build_gemm_kernel(
    const float* __restrict__ X, const float* __restrict__ W,
    const float* __restrict__ b, float* __restrict__ H, int nrows,
    const int* __restrict__ row, const int* __restrict__ col,
    const float* __restrict__ ew,
    float* __restrict__ deg, int* __restrict__ cnt, int2* __restrict__ csr,
    int E, int gemmBlocks)
{
    __shared__ float Xs[64 * DF];
    __shared__ float Wsk[32 * DF];

    const int tid = threadIdx.x;

    if (blockIdx.x >= gemmBlocks) {
        // ---------------- build part: 1 edge per thread ----------------
        int e = (blockIdx.x - gemmBlocks) * 256 + tid;
        if (e < E) {
            int r = row[e], c = col[e];
            float wv = ew[e];
            atomicAdd(&deg[r], wv);              // fire-and-forget
            int pos = atomicAdd(&cnt[c], 1);     // returning
            if (pos < CAP)
                csr[(size_t)c * CAP + pos] = make_int2(r, __float_as_int(wv));
        }
        return;
    }

    // ---------------- gemm part: stage X tile, then shared GEMM core ----
    const int n0 = blockIdx.x * 64;
#pragma unroll
    for (int i = 0; i < 8; ++i) {
        int idx = tid + i * 256;
        int r   = idx >> 5;
        int kk  = idx & 31;
        int n   = n0 + r;
        float4 v = make_float4(0.f, 0.f, 0.f, 0.f);
        if (n < nrows) v = ((const float4*)(X + (size_t)n * DF))[kk];
        ((float4*)Xs)[idx] = v;
    }
    gemm_from_lds<8, false>(Xs, Wsk, W, b, H, nrows, n0, tid, nullptr);
}

// ==== fused layer boundary: agg1 (+ReLU) -> LDS -> GEMM2, 64-row tile ====
// R15: tile 32->64 rows. Each 32-lane group aggregates its 8 rows as 4
// interleaved pairs (agg2 — measured best). Halves per-output Wsk stagings,
// barriers and W2 re-fetch vs the 32-row tile. LDS 48KB (cap 3 blocks/CU
// ~ measured 33% occupancy, so the cap barely binds).
// Output h2 rows pre-scaled by rsqrt(deg[row]) in the epilogue.
__global__ __launch_bounds__(256) void agg_gemm_kernel(
    const float4* __restrict__ H4,      // layer-1 linear output (gather src)
    const int2* __restrict__ csr, const int* __restrict__ cnt,
    const float* __restrict__ deg,
    const float* __restrict__ W, const float* __restrict__ b,
    float* __restrict__ O, int N)
{
    __shared__ float Xs[64 * DF];
    __shared__ float Wsk[32 * DF];

    const int tid = threadIdx.x;
    const int g   = tid >> 5;        // group 0..7, owns rows g*8 .. g*8+7
    const int t   = tid & 31;
    const int n0  = blockIdx.x * 64;

#pragma unroll
    for (int jp = 0; jp < 4; ++jp) {
        const int rA = g * 8 + jp * 2;
        const int rB = rA + 1;
        const int nodeA = n0 + rA;
        const int nodeB = n0 + rB;
        int mA = 0, mB = 0;
        if (nodeA < N) { mA = cnt[nodeA]; if (mA > CAP) mA = CAP; }
        if (nodeB < N) { mB = cnt[nodeB]; if (mB > CAP) mB = CAP; }
        // clamp pointer bases for OOB rows (m=0 -> never dereferenced)
        const int lim = N - 1;
        const int2* bA = csr + (size_t)(nodeA < N ? nodeA : lim) * CAP;
        const int2* bB = csr + (size_t)(nodeB < N ? nodeB : lim) * CAP;
        float4 accA = make_float4(0.f, 0.f, 0.f, 0.f);
        float4 accB = make_float4(0.f, 0.f, 0.f, 0.f);
        agg2<false>(H4, bA, mA, bB, mB, deg, t, accA, accB);
        if (nodeA < N) {
            const float d = rsqrtf(deg[nodeA]);
            accA.x = fmaxf(accA.x * d, 0.f); accA.y = fmaxf(accA.y * d, 0.f);
            accA.z = fmaxf(accA.z * d, 0.f); accA.w = fmaxf(accA.w * d, 0.f);
        }
        if (nodeB < N) {
            const float d = rsqrtf(deg[nodeB]);
            accB.x = fmaxf(accB.x * d, 0.f); accB.y = fmaxf(accB.y * d, 0.f);
            accB.z = fmaxf(accB.z * d, 0.f); accB.w = fmaxf(accB.w * d, 0.f);
        }
        ((float4*)Xs)[rA * 32 + t] = accA;   // zeros for OOB rows
        ((float4*)Xs)[rB * 32 + t] = accB;
    }
    // (first __syncthreads inside gemm_from_lds's k0 loop fences Xs writes)
    gemm_from_lds<8, true>(Xs, Wsk, W, b, O, N, n0, tid, deg);
}

// ---- final pull aggregation: 2 nodes per half-wave; h2 is pre-scaled ----
__global__ __launch_bounds__(256) void agg_kernel(
    const float4* __restrict__ H4,
    const int2* __restrict__ csr, const int* __restrict__ cnt,
    const float* __restrict__ deg,
    float4* __restrict__ O4, int N)
{
    const int gid  = blockIdx.x * blockDim.x + threadIdx.x;
    const int half = gid >> 5;
    const int t    = gid & 31;
    const int nA   = half * 2;
    const int nB   = nA + 1;
    if (nA >= N) return;
    int mA = cnt[nA]; if (mA > CAP) mA = CAP;
    int mB = 0;
    if (nB < N) { mB = cnt[nB]; if (mB > CAP) mB = CAP; }
    const int2* bA = csr + (size_t)nA * CAP;
    const int2* bB = csr + (size_t)(nB < N ? nB : (N - 1)) * CAP;
    float4 accA = make_float4(0.f, 0.f, 0.f, 0.f);
    float4 accB = make_float4(0.f, 0.f, 0.f, 0.f);
    agg2<true>(H4, bA, mA, bB, mB, deg, t, accA, accB);
    const float dA = rsqrtf(deg[nA]);
    accA.x *= dA; accA.y *= dA; accA.z *= dA; accA.w *= dA;
    O4[(size_t)nA * 32 + t] = accA;
    if (nB < N) {
        const float dB = rsqrtf(deg[nB]);
        accB.x *= dB; accB.y *= dB; accB.z *= dB; accB.w *= dB;
        O4[(size_t)nB * 32 + t] = accB;
    }
}

extern "C" void kernel_launch(void* const* d_in, const int* in_sizes, int n_in,
                              void* d_out, int out_size, void* d_ws, size_t ws_size,
                              hipStream_t stream) {
    const float* x  = (const float*)d_in[0];
    const int*   ei = (const int*)d_in[1];
    const float* ew = (const float*)d_in[2];
    const float* W1 = (const float*)d_in[3];
    const float* b1 = (const float*)d_in[4];
    const float* W2 = (const float*)d_in[5];
    const float* b2 = (const float*)d_in[6];
    float* out = (float*)d_out;

    const int E = in_sizes[2];        // 600000
    const int N = in_sizes[0] / DF;   // 50000
    const int* row = ei;
    const int* col = ei + E;

    char* ws = (char*)d_ws;
    size_t offb = 0;
    auto alloc = [&](size_t bytes) { char* p = ws + offb; offb = (offb + bytes + 511) & ~(size_t)511; return p; };
    float* deg  = (float*)alloc((size_t)2 * N * 4);      // deg | cnt combined (one memset)
    int*   cnt  = (int*)(deg + N);
    int2*  csr  = (int2*)alloc((size_t)N * CAP * 8);     // packed (src, w) records
    float* h1   = (float*)alloc((size_t)N * DF * 4);     // layer-1 linear out
    float* h2   = (float*)alloc((size_t)N * DF * 4);     // layer-2 linear out (pre-scaled by rsqrt(deg))
    (void)ws_size;

    hipMemsetAsync(deg, 0, (size_t)2 * N * 4, stream);

    const int TB = 256;
    const int eblocks = (E + TB - 1) / TB;               // 1 edge per thread
    const int gemm1_blocks = (N + 63) / 64;              // 64-row tiles
    const int agg_gemm_blocks = (N + 63) / 64;           // 64-row tiles (R15)

    // ---- fused: gemm1 + CSR build ----
    build_gemm_kernel<<<gemm1_blocks + eblocks, 256, 0, stream>>>(
        x, W1, b1, h1, N, row, col, ew, deg, cnt, csr, E, gemm1_blocks);

    // ---- fused: agg1 (+ReLU) -> LDS -> gemm2 (pre-scaled output) ----
    agg_gemm_kernel<<<agg_gemm_blocks, 256, 0, stream>>>(
        (const float4*)h1, csr, cnt, deg, W2, b2, h2, N);

    // ---- final aggregation: 2 nodes per half-wave ----
    const int pairs = (N + 1) / 2;
    const int agg_blocks = (pairs * 32 + TB - 1) / TB;
    agg_kernel<<<agg_blocks, TB, 0, stream>>>((const float4*)h2, csr, cnt, deg,
                                              (float4*)out, N);
}

// Round 16
// 280.471 us; speedup vs baseline: 1.0857x; 1.0857x over previous
//
#include <hip/hip_runtime.h>

#define DF 128
#define CAP 32    // bucket capacity; in-deg ~ Poisson(12), realized max ~30 (prior
                  // session's measurement). 32 => 256B power-of-2 buckets: line-
                  // aligned, shift addressing, csr 16->12.8MB. Failure is LOUD
                  // (dropped records -> absmax blowup) -> revert to 40 if so.

// NOTE: parameter names must not collide with float4 member names (x,y,z,w):
// macro substitution rewrites identifiers even after '.', so a param named
// 'w' would turn 'v.w' into 'v.<arg>'.
#define FMA4(a4, s, v)                                              \
    a4.x = fmaf(s, v.x, a4.x); a4.y = fmaf(s, v.y, a4.y);           \
    a4.z = fmaf(s, v.z, a4.z); a4.w = fmaf(s, v.w, a4.w)

// ---------------------------------------------------------------------------
// MEASURED HISTORY (do not re-try without new evidence):
//  - R10 config (this file, CAP=40) = 281.6us, measured twice. BEST.
//  - 4-edge-per-thread build: REGRESSION (83.6 -> 91.8us). 1 edge/thr.
//  - agg4 (4-node interleave): REGRESSION vs agg2. Keep agg2.
//  - agg2 (2-node interleave): WIN (agg_gemm 108 -> <83.6us).
//  - h2 pre-scale (SCALE_OUT epilogue): WIN component of R10 best.
//  - direct-X gemm1 (R11): REGRESSION (global broadcast loads stall).
//  - split build/gemm1 (R14): REGRESSION 304 (+23us lost overlap/launch).
//    Build is atomic/fabric-throughput-bound; occupancy/MLP levers dead.
//  - 64-row agg_gemm tile (R15): REGRESSION 103-110us (occ 33->15.6%).
//    Agg phase needs occupancy, not staging amortization. 32-row tile.
//  - R16 experiment: CAP 40->32 (alignment/footprint only).
// ---------------------------------------------------------------------------

// ---------------------------------------------------------------------------
// 4-way-unrolled tail aggregation starting at record i:
//   SCALED=false: acc += sum w_i * rsqrt(deg[src_i]) * H[src_i][4t..4t+3]
//   SCALED=true:  acc += sum w_i * H[src_i][...]   (H rows pre-scaled)
// bucket is 16B-aligned (csr base 512B-aligned, node*CAP*8 = node*256).
// ---------------------------------------------------------------------------
template <bool SCALED>
__device__ __forceinline__ float4 agg_tail(const float4* __restrict__ H4,
                                           const int2* __restrict__ bucket,
                                           int i, int m,
                                           const float* __restrict__ deg,
                                           int t, float4 acc)
{
    for (; i + 4 <= m; i += 4) {
        const int4* b4 = (const int4*)(bucket + i);
        const int4 p0 = b4[0];
        const int4 p1 = b4[1];
        const float4 h0 = H4[(size_t)p0.x * 32 + t];
        const float4 h1 = H4[(size_t)p0.z * 32 + t];
        const float4 h2 = H4[(size_t)p1.x * 32 + t];
        const float4 h3 = H4[(size_t)p1.z * 32 + t];
        const float s0 = SCALED ? __int_as_float(p0.y) : __int_as_float(p0.y) * rsqrtf(deg[p0.x]);
        const float s1 = SCALED ? __int_as_float(p0.w) : __int_as_float(p0.w) * rsqrtf(deg[p0.z]);
        const float s2 = SCALED ? __int_as_float(p1.y) : __int_as_float(p1.y) * rsqrtf(deg[p1.x]);
        const float s3 = SCALED ? __int_as_float(p1.w) : __int_as_float(p1.w) * rsqrtf(deg[p1.z]);
        FMA4(acc, s0, h0);
        FMA4(acc, s1, h1);
        FMA4(acc, s2, h2);
        FMA4(acc, s3, h3);
    }
    for (; i < m; ++i) {
        const int2 rec = bucket[i];
        const float sv = SCALED ? __int_as_float(rec.y) : __int_as_float(rec.y) * rsqrtf(deg[rec.x]);
        const float4 hv = H4[(size_t)rec.x * 32 + t];
        FMA4(acc, sv, hv);
    }
    return acc;
}

// ---------------------------------------------------------------------------
// Two-node interleaved aggregation: 8 independent 512B gathers in flight per
// iteration over the common prefix, then per-node tails. Summation order
// within each node is unchanged.
// ---------------------------------------------------------------------------
template <bool SCALED>
__device__ __forceinline__ void agg2(const float4* __restrict__ H4,
                                     const int2* __restrict__ bA, int mA,
                                     const int2* __restrict__ bB, int mB,
                                     const float* __restrict__ deg, int t,
                                     float4& accA, float4& accB)
{
    const int mc = mA < mB ? mA : mB;
    int i = 0;
    for (; i + 4 <= mc; i += 4) {
        const int4 a0 = ((const int4*)(bA + i))[0];
        const int4 a1 = ((const int4*)(bA + i))[1];
        const int4 c0 = ((const int4*)(bB + i))[0];
        const int4 c1 = ((const int4*)(bB + i))[1];
        const float4 hA0 = H4[(size_t)a0.x * 32 + t];
        const float4 hA1 = H4[(size_t)a0.z * 32 + t];
        const float4 hA2 = H4[(size_t)a1.x * 32 + t];
        const float4 hA3 = H4[(size_t)a1.z * 32 + t];
        const float4 hB0 = H4[(size_t)c0.x * 32 + t];
        const float4 hB1 = H4[(size_t)c0.z * 32 + t];
        const float4 hB2 = H4[(size_t)c1.x * 32 + t];
        const float4 hB3 = H4[(size_t)c1.z * 32 + t];
        const float sA0 = SCALED ? __int_as_float(a0.y) : __int_as_float(a0.y) * rsqrtf(deg[a0.x]);
        const float sA1 = SCALED ? __int_as_float(a0.w) : __int_as_float(a0.w) * rsqrtf(deg[a0.z]);
        const float sA2 = SCALED ? __int_as_float(a1.y) : __int_as_float(a1.y) * rsqrtf(deg[a1.x]);
        const float sA3 = SCALED ? __int_as_float(a1.w) : __int_as_float(a1.w) * rsqrtf(deg[a1.z]);
        const float sB0 = SCALED ? __int_as_float(c0.y) : __int_as_float(c0.y) * rsqrtf(deg[c0.x]);
        const float sB1 = SCALED ? __int_as_float(c0.w) : __int_as_float(c0.w) * rsqrtf(deg[c0.z]);
        const float sB2 = SCALED ? __int_as_float(c1.y) : __int_as_float(c1.y) * rsqrtf(deg[c1.x]);
        const float sB3 = SCALED ? __int_as_float(c1.w) : __int_as_float(c1.w) * rsqrtf(deg[c1.z]);
        FMA4(accA, sA0, hA0);
        FMA4(accA, sA1, hA1);
        FMA4(accA, sA2, hA2);
        FMA4(accA, sA3, hA3);
        FMA4(accB, sB0, hB0);
        FMA4(accB, sB1, hB1);
        FMA4(accB, sB2, hB2);
        FMA4(accB, sB3, hB3);
    }
    accA = agg_tail<SCALED>(H4, bA, i, mA, deg, t, accA);
    accB = agg_tail<SCALED>(H4, bB, i, mB, deg, t, accB);
}

// ---------------------------------------------------------------------------
// Register-blocked GEMM core: H[n0 : n0+8*RPT] = Xs @ W^T + b.
// RPT = rows per thread (= rows per 32-lane group). Xs is (8*RPT) x 128
// row-major in LDS, fully populated by the caller (first __syncthreads in
// the k0 loop fences it). Wsk is a 32 x 128 k-slice of W, transposed.
// SCALE_OUT: multiply output row n by rsqrt(degv[n]) before the store.
// ---------------------------------------------------------------------------
template <int RPT, bool SCALE_OUT>
__device__ __forceinline__ void gemm_from_lds(
    float* __restrict__ Xs, float* __restrict__ Wsk,
    const float* __restrict__ W, const float* __restrict__ b,
    float* __restrict__ H, int nrows, int n0, int tid,
    const float* __restrict__ degv)
{
    const int rgrp = tid >> 5;
    const int cgrp = tid & 31;

    float4 acc[RPT];
    const float4 bias = ((const float4*)b)[cgrp];
#pragma unroll
    for (int r = 0; r < RPT; ++r) acc[r] = bias;

    const float4* Xs4 = (const float4*)Xs;
    const float4* Ws4 = (const float4*)Wsk;

    for (int k0 = 0; k0 < DF; k0 += 32) {
        __syncthreads();
#pragma unroll
        for (int i = 0; i < 4; ++i) {
            int idx = tid + i * 256;
            int c   = idx >> 3;
            int kk  = idx & 7;
            float4 v = ((const float4*)(W + (size_t)c * DF + k0))[kk];
            int kb = kk * 4;
            Wsk[(kb + 0) * DF + c] = v.x;
            Wsk[(kb + 1) * DF + c] = v.y;
            Wsk[(kb + 2) * DF + c] = v.z;
            Wsk[(kb + 3) * DF + c] = v.w;
        }
        __syncthreads();

#pragma unroll
        for (int kk = 0; kk < 8; ++kk) {
            const int kb = (k0 >> 2) + kk;
            float4 w0 = Ws4[(kk * 4 + 0) * 32 + cgrp];
            float4 w1 = Ws4[(kk * 4 + 1) * 32 + cgrp];
            float4 w2 = Ws4[(kk * 4 + 2) * 32 + cgrp];
            float4 w3 = Ws4[(kk * 4 + 3) * 32 + cgrp];
#pragma unroll
            for (int r = 0; r < RPT; ++r) {
                float4 x4 = Xs4[(rgrp * RPT + r) * 32 + kb];
                acc[r].x = fmaf(x4.x, w0.x, acc[r].x);
                acc[r].y = fmaf(x4.x, w0.y, acc[r].y);
                acc[r].z = fmaf(x4.x, w0.z, acc[r].z);
                acc[r].w = fmaf(x4.x, w0.w, acc[r].w);
                acc[r].x = fmaf(x4.y, w1.x, acc[r].x);
                acc[r].y = fmaf(x4.y, w1.y, acc[r].y);
                acc[r].z = fmaf(x4.y, w1.z, acc[r].z);
                acc[r].w = fmaf(x4.y, w1.w, acc[r].w);
                acc[r].x = fmaf(x4.z, w2.x, acc[r].x);
                acc[r].y = fmaf(x4.z, w2.y, acc[r].y);
                acc[r].z = fmaf(x4.z, w2.z, acc[r].z);
                acc[r].w = fmaf(x4.z, w2.w, acc[r].w);
                acc[r].x = fmaf(x4.w, w3.x, acc[r].x);
                acc[r].y = fmaf(x4.w, w3.y, acc[r].y);
                acc[r].z = fmaf(x4.w, w3.z, acc[r].z);
                acc[r].w = fmaf(x4.w, w3.w, acc[r].w);
            }
        }
    }

#pragma unroll
    for (int r = 0; r < RPT; ++r) {
        int n = n0 + rgrp * RPT + r;
        if (n < nrows) {
            if (SCALE_OUT) {
                const float d = rsqrtf(degv[n]);
                acc[r].x *= d; acc[r].y *= d; acc[r].z *= d; acc[r].w *= d;
            }
            ((float4*)(H + (size_t)n * DF))[cgrp] = acc[r];
        }
    }
}

// ==== fused: blocks [0,gemmBlocks) = GEMM1 64-row tile; rest = CSR build ====
// 64-row tile + 1-edge-per-thread build: R10-measured best (281.6us total,
// this kernel 84us). Build is fabric-bound (R14) — keep fused for overlap.
__global__ __launch_bounds__(256) void build_gemm_kernel(
    const float* __restrict__ X, const float* __restrict__ W,
    const float* __restrict__ b, float* __restrict__ H, int nrows,
    const int* __restrict__ row, const int* __restrict__ col,
    const float* __restrict__ ew,
    float* __restrict__ deg, int* __restrict__ cnt, int2* __restrict__ csr,
    int E, int gemmBlocks)
{
    __shared__ float Xs[64 * DF];
    __shared__ float Wsk[32 * DF];

    const int tid = threadIdx.x;

    if (blockIdx.x >= gemmBlocks) {
        // ---------------- build part: 1 edge per thread ----------------
        int e = (blockIdx.x - gemmBlocks) * 256 + tid;
        if (e < E) {
            int r = row[e], c = col[e];
            float wv = ew[e];
            atomicAdd(&deg[r], wv);              // fire-and-forget
            int pos = atomicAdd(&cnt[c], 1);     // returning
            if (pos < CAP)
                csr[(size_t)c * CAP + pos] = make_int2(r, __float_as_int(wv));
        }
        return;
    }

    // ---------------- gemm part: stage X tile, then shared GEMM core ----
    const int n0 = blockIdx.x * 64;
#pragma unroll
    for (int i = 0; i < 8; ++i) {
        int idx = tid + i * 256;
        int r   = idx >> 5;
        int kk  = idx & 31;
        int n   = n0 + r;
        float4 v = make_float4(0.f, 0.f, 0.f, 0.f);
        if (n < nrows) v = ((const float4*)(X + (size_t)n * DF))[kk];
        ((float4*)Xs)[idx] = v;
    }
    gemm_from_lds<8, false>(Xs, Wsk, W, b, H, nrows, n0, tid, nullptr);
}

// ==== fused layer boundary: agg1 (+ReLU) -> LDS -> GEMM2, 32-row tile ====
// 32-row tile (32KB LDS) measured best for the gather-dominated phase
// (R15: 64-row tile dropped occupancy 33->15.6% and cost +25us).
// Each 32-lane group aggregates its 4 rows as 2 interleaved pairs (agg2).
// Output h2 rows pre-scaled by rsqrt(deg[row]) in the epilogue.
__global__ __launch_bounds__(256) void agg_gemm_kernel(
    const float4* __restrict__ H4,      // layer-1 linear output (gather src)
    const int2* __restrict__ csr, const int* __restrict__ cnt,
    const float* __restrict__ deg,
    const float* __restrict__ W, const float* __restrict__ b,
    float* __restrict__ O, int N)
{
    __shared__ float Xs[32 * DF];
    __shared__ float Wsk[32 * DF];

    const int tid = threadIdx.x;
    const int g   = tid >> 5;        // group 0..7, owns rows g*4 .. g*4+3
    const int t   = tid & 31;
    const int n0  = blockIdx.x * 32;

#pragma unroll
    for (int jp = 0; jp < 2; ++jp) {
        const int rA = g * 4 + jp * 2;
        const int rB = rA + 1;
        const int nodeA = n0 + rA;
        const int nodeB = n0 + rB;
        int mA = 0, mB = 0;
        if (nodeA < N) { mA = cnt[nodeA]; if (mA > CAP) mA = CAP; }
        if (nodeB < N) { mB = cnt[nodeB]; if (mB > CAP) mB = CAP; }
        // clamp pointer bases for OOB rows (m=0 -> never dereferenced)
        const int lim = N - 1;
        const int2* bA = csr + (size_t)(nodeA < N ? nodeA : lim) * CAP;
        const int2* bB = csr + (size_t)(nodeB < N ? nodeB : lim) * CAP;
        float4 accA = make_float4(0.f, 0.f, 0.f, 0.f);
        float4 accB = make_float4(0.f, 0.f, 0.f, 0.f);
        agg2<false>(H4, bA, mA, bB, mB, deg, t, accA, accB);
        if (nodeA < N) {
            const float d = rsqrtf(deg[nodeA]);
            accA.x = fmaxf(accA.x * d, 0.f); accA.y = fmaxf(accA.y * d, 0.f);
            accA.z = fmaxf(accA.z * d, 0.f); accA.w = fmaxf(accA.w * d, 0.f);
        }
        if (nodeB < N) {
            const float d = rsqrtf(deg[nodeB]);
            accB.x = fmaxf(accB.x * d, 0.f); accB.y = fmaxf(accB.y * d, 0.f);
            accB.z = fmaxf(accB.z * d, 0.f); accB.w = fmaxf(accB.w * d, 0.f);
        }
        ((float4*)Xs)[rA * 32 + t] = accA;   // zeros for OOB rows
        ((float4*)Xs)[rB * 32 + t] = accB;
    }
    // (first __syncthreads inside gemm_from_lds's k0 loop fences Xs writes)
    gemm_from_lds<4, true>(Xs, Wsk, W, b, O, N, n0, tid, deg);
}

// ---- final pull aggregation: 2 nodes per half-wave; h2 is pre-scaled ----
__global__ __launch_bounds__(256) void agg_kernel(
    const float4* __restrict__ H4,
    const int2* __restrict__ csr, const int* __restrict__ cnt,
    const float* __restrict__ deg,
    float4* __restrict__ O4, int N)
{
    const int gid  = blockIdx.x * blockDim.x + threadIdx.x;
    const int half = gid >> 5;
    const int t    = gid & 31;
    const int nA   = half * 2;
    const int nB   = nA + 1;
    if (nA >= N) return;
    int mA = cnt[nA]; if (mA > CAP) mA = CAP;
    int mB = 0;
    if (nB < N) { mB = cnt[nB]; if (mB > CAP) mB = CAP; }
    const int2* bA = csr + (size_t)nA * CAP;
    const int2* bB = csr + (size_t)(nB < N ? nB : (N - 1)) * CAP;
    float4 accA = make_float4(0.f, 0.f, 0.f, 0.f);
    float4 accB = make_float4(0.f, 0.f, 0.f, 0.f);
    agg2<true>(H4, bA, mA, bB, mB, deg, t, accA, accB);
    const float dA = rsqrtf(deg[nA]);
    accA.x *= dA; accA.y *= dA; accA.z *= dA; accA.w *= dA;
    O4[(size_t)nA * 32 + t] = accA;
    if (nB < N) {
        const float dB = rsqrtf(deg[nB]);
        accB.x *= dB; accB.y *= dB; accB.z *= dB; accB.w *= dB;
        O4[(size_t)nB * 32 + t] = accB;
    }
}

extern "C" void kernel_launch(void* const* d_in, const int* in_sizes, int n_in,
                              void* d_out, int out_size, void* d_ws, size_t ws_size,
                              hipStream_t stream) {
    const float* x  = (const float*)d_in[0];
    const int*   ei = (const int*)d_in[1];
    const float* ew = (const float*)d_in[2];
    const float* W1 = (const float*)d_in[3];
    const float* b1 = (const float*)d_in[4];
    const float* W2 = (const float*)d_in[5];
    const float* b2 = (const float*)d_in[6];
    float* out = (float*)d_out;

    const int E = in_sizes[2];        // 600000
    const int N = in_sizes[0] / DF;   // 50000
    const int* row = ei;
    const int* col = ei + E;

    char* ws = (char*)d_ws;
    size_t offb = 0;
    auto alloc = [&](size_t bytes) { char* p = ws + offb; offb = (offb + bytes + 511) & ~(size_t)511; return p; };
    float* deg  = (float*)alloc((size_t)2 * N * 4);      // deg | cnt combined (one memset)
    int*   cnt  = (int*)(deg + N);
    int2*  csr  = (int2*)alloc((size_t)N * CAP * 8);     // packed (src, w) records
    float* h1   = (float*)alloc((size_t)N * DF * 4);     // layer-1 linear out
    float* h2   = (float*)alloc((size_t)N * DF * 4);     // layer-2 linear out (pre-scaled by rsqrt(deg))
    (void)ws_size;

    hipMemsetAsync(deg, 0, (size_t)2 * N * 4, stream);

    const int TB = 256;
    const int eblocks = (E + TB - 1) / TB;               // 1 edge per thread
    const int gemm1_blocks = (N + 63) / 64;              // 64-row tiles
    const int agg_gemm_blocks = (N + 31) / 32;           // 32-row tiles

    // ---- fused: gemm1 + CSR build ----
    build_gemm_kernel<<<gemm1_blocks + eblocks, 256, 0, stream>>>(
        x, W1, b1, h1, N, row, col, ew, deg, cnt, csr, E, gemm1_blocks);

    // ---- fused: agg1 (+ReLU) -> LDS -> gemm2 (pre-scaled output) ----
    agg_gemm_kernel<<<agg_gemm_blocks, 256, 0, stream>>>(
        (const float4*)h1, csr, cnt, deg, W2, b2, h2, N);

    // ---- final aggregation: 2 nodes per half-wave ----
    const int pairs = (N + 1) / 2;
    const int agg_blocks = (pairs * 32 + TB - 1) / TB;
    agg_kernel<<<agg_blocks, TB, 0, stream>>>((const float4*)h2, csr, cnt, deg,
                                              (float4*)out, N);
}

// Round 17
// 257.443 us; speedup vs baseline: 1.1828x; 1.0895x over previous
//
#include <hip/hip_runtime.h>
#include <hip/hip_fp16.h>

#define DF 128
#define CAP 32    // bucket capacity (R16-verified: passes, 256B aligned buckets)

// NOTE: parameter names must not collide with float4 member names (x,y,z,w):
// macro substitution rewrites identifiers even after '.'.
#define FMA4(a4, s, v)                                              \
    a4.x = fmaf(s, v.x, a4.x); a4.y = fmaf(s, v.y, a4.y);           \
    a4.z = fmaf(s, v.z, a4.z); a4.w = fmaf(s, v.w, a4.w)

// ---------------------------------------------------------------------------
// MEASURED HISTORY (do not re-try without new evidence):
//  - R16 config (CAP=32, fp32 h) = 280.5us. BEST so far, banked.
//  - 4-edge-per-thread build: REGRESSION (83.6 -> 91.8). 1 edge/thr.
//  - agg4: REGRESSION vs agg2 (min-of-4 shrinks interleave prefix).
//  - agg2: WIN. h2 pre-scale epilogue: WIN.
//  - direct-X gemm1 (R11): REGRESSION. split build/gemm1 (R14): REGRESSION
//    (+23us). Build is atomic/fabric-bound; occupancy/MLP levers dead.
//  - 64-row agg_gemm tile (R15): REGRESSION (occ 33->15.6%). 32-row tile.
//  - R17 experiment: h1/h2 in fp16. Agg is L3-BW-bound (307MB gather volume
//    per pass at ~3.9TB/s effective); fp16 halves it. Revert if absmax fails.
// ---------------------------------------------------------------------------

// fp16 row helpers: lane t owns halves [t*4, t*4+4) of a 128-half row (8B).
__device__ __forceinline__ float4 h4_to_f4(uint2 u) {
    __half2 a = *(__half2*)&u.x;
    __half2 b = *(__half2*)&u.y;
    float2 fa = __half22float2(a);
    float2 fb = __half22float2(b);
    return make_float4(fa.x, fa.y, fb.x, fb.y);
}
__device__ __forceinline__ uint2 f4_to_h4(float4 v) {
    __half2 a = __floats2half2_rn(v.x, v.y);
    __half2 b = __floats2half2_rn(v.z, v.w);
    uint2 u;
    u.x = *(unsigned int*)&a;
    u.y = *(unsigned int*)&b;
    return u;
}

// ---------------------------------------------------------------------------
// 4-way-unrolled tail aggregation starting at record i (fp16 H rows):
//   SCALED=false: acc += sum w_i * rsqrt(deg[src_i]) * H[src_i][4t..4t+3]
//   SCALED=true:  acc += sum w_i * H[src_i][...]   (H rows pre-scaled)
// Hh indexed in uint2 units: row*32 + t. bucket is 16B-aligned.
// ---------------------------------------------------------------------------
template <bool SCALED>
__device__ __forceinline__ float4 agg_tail(const uint2* __restrict__ Hh,
                                           const int2* __restrict__ bucket,
                                           int i, int m,
                                           const float* __restrict__ deg,
                                           int t, float4 acc)
{
    for (; i + 4 <= m; i += 4) {
        const int4* b4 = (const int4*)(bucket + i);
        const int4 p0 = b4[0];
        const int4 p1 = b4[1];
        const uint2 u0 = Hh[(size_t)p0.x * 32 + t];
        const uint2 u1 = Hh[(size_t)p0.z * 32 + t];
        const uint2 u2 = Hh[(size_t)p1.x * 32 + t];
        const uint2 u3 = Hh[(size_t)p1.z * 32 + t];
        const float s0 = SCALED ? __int_as_float(p0.y) : __int_as_float(p0.y) * rsqrtf(deg[p0.x]);
        const float s1 = SCALED ? __int_as_float(p0.w) : __int_as_float(p0.w) * rsqrtf(deg[p0.z]);
        const float s2 = SCALED ? __int_as_float(p1.y) : __int_as_float(p1.y) * rsqrtf(deg[p1.x]);
        const float s3 = SCALED ? __int_as_float(p1.w) : __int_as_float(p1.w) * rsqrtf(deg[p1.z]);
        const float4 h0 = h4_to_f4(u0);
        const float4 h1 = h4_to_f4(u1);
        const float4 h2 = h4_to_f4(u2);
        const float4 h3 = h4_to_f4(u3);
        FMA4(acc, s0, h0);
        FMA4(acc, s1, h1);
        FMA4(acc, s2, h2);
        FMA4(acc, s3, h3);
    }
    for (; i < m; ++i) {
        const int2 rec = bucket[i];
        const float sv = SCALED ? __int_as_float(rec.y) : __int_as_float(rec.y) * rsqrtf(deg[rec.x]);
        const float4 hv = h4_to_f4(Hh[(size_t)rec.x * 32 + t]);
        FMA4(acc, sv, hv);
    }
    return acc;
}

// ---------------------------------------------------------------------------
// Two-node interleaved aggregation: 8 independent 256B gathers in flight per
// iteration over the common prefix, then per-node tails.
// ---------------------------------------------------------------------------
template <bool SCALED>
__device__ __forceinline__ void agg2(const uint2* __restrict__ Hh,
                                     const int2* __restrict__ bA, int mA,
                                     const int2* __restrict__ bB, int mB,
                                     const float* __restrict__ deg, int t,
                                     float4& accA, float4& accB)
{
    const int mc = mA < mB ? mA : mB;
    int i = 0;
    for (; i + 4 <= mc; i += 4) {
        const int4 a0 = ((const int4*)(bA + i))[0];
        const int4 a1 = ((const int4*)(bA + i))[1];
        const int4 c0 = ((const int4*)(bB + i))[0];
        const int4 c1 = ((const int4*)(bB + i))[1];
        const uint2 uA0 = Hh[(size_t)a0.x * 32 + t];
        const uint2 uA1 = Hh[(size_t)a0.z * 32 + t];
        const uint2 uA2 = Hh[(size_t)a1.x * 32 + t];
        const uint2 uA3 = Hh[(size_t)a1.z * 32 + t];
        const uint2 uB0 = Hh[(size_t)c0.x * 32 + t];
        const uint2 uB1 = Hh[(size_t)c0.z * 32 + t];
        const uint2 uB2 = Hh[(size_t)c1.x * 32 + t];
        const uint2 uB3 = Hh[(size_t)c1.z * 32 + t];
        const float sA0 = SCALED ? __int_as_float(a0.y) : __int_as_float(a0.y) * rsqrtf(deg[a0.x]);
        const float sA1 = SCALED ? __int_as_float(a0.w) : __int_as_float(a0.w) * rsqrtf(deg[a0.z]);
        const float sA2 = SCALED ? __int_as_float(a1.y) : __int_as_float(a1.y) * rsqrtf(deg[a1.x]);
        const float sA3 = SCALED ? __int_as_float(a1.w) : __int_as_float(a1.w) * rsqrtf(deg[a1.z]);
        const float sB0 = SCALED ? __int_as_float(c0.y) : __int_as_float(c0.y) * rsqrtf(deg[c0.x]);
        const float sB1 = SCALED ? __int_as_float(c0.w) : __int_as_float(c0.w) * rsqrtf(deg[c0.z]);
        const float sB2 = SCALED ? __int_as_float(c1.y) : __int_as_float(c1.y) * rsqrtf(deg[c1.x]);
        const float sB3 = SCALED ? __int_as_float(c1.w) : __int_as_float(c1.w) * rsqrtf(deg[c1.z]);
        const float4 hA0 = h4_to_f4(uA0);
        const float4 hA1 = h4_to_f4(uA1);
        const float4 hA2 = h4_to_f4(uA2);
        const float4 hA3 = h4_to_f4(uA3);
        const float4 hB0 = h4_to_f4(uB0);
        const float4 hB1 = h4_to_f4(uB1);
        const float4 hB2 = h4_to_f4(uB2);
        const float4 hB3 = h4_to_f4(uB3);
        FMA4(accA, sA0, hA0);
        FMA4(accA, sA1, hA1);
        FMA4(accA, sA2, hA2);
        FMA4(accA, sA3, hA3);
        FMA4(accB, sB0, hB0);
        FMA4(accB, sB1, hB1);
        FMA4(accB, sB2, hB2);
        FMA4(accB, sB3, hB3);
    }
    accA = agg_tail<SCALED>(Hh, bA, i, mA, deg, t, accA);
    accB = agg_tail<SCALED>(Hh, bB, i, mB, deg, t, accB);
}

// ---------------------------------------------------------------------------
// Register-blocked GEMM core: H[n0 : n0+8*RPT] = Xs @ W^T + b, H in fp16.
// RPT = rows per thread-group. Xs is (8*RPT) x 128 row-major in LDS (fp32),
// fully populated by the caller. Wsk is a 32 x 128 k-slice of W, transposed.
// SCALE_OUT: multiply output row n by rsqrt(degv[n]) before the store.
// ---------------------------------------------------------------------------
template <int RPT, bool SCALE_OUT>
__device__ __forceinline__ void gemm_from_lds(
    float* __restrict__ Xs, float* __restrict__ Wsk,
    const float* __restrict__ W, const float* __restrict__ b,
    __half* __restrict__ H, int nrows, int n0, int tid,
    const float* __restrict__ degv)
{
    const int rgrp = tid >> 5;
    const int cgrp = tid & 31;

    float4 acc[RPT];
    const float4 bias = ((const float4*)b)[cgrp];
#pragma unroll
    for (int r = 0; r < RPT; ++r) acc[r] = bias;

    const float4* Xs4 = (const float4*)Xs;
    const float4* Ws4 = (const float4*)Wsk;

    for (int k0 = 0; k0 < DF; k0 += 32) {
        __syncthreads();
#pragma unroll
        for (int i = 0; i < 4; ++i) {
            int idx = tid + i * 256;
            int c   = idx >> 3;
            int kk  = idx & 7;
            float4 v = ((const float4*)(W + (size_t)c * DF + k0))[kk];
            int kb = kk * 4;
            Wsk[(kb + 0) * DF + c] = v.x;
            Wsk[(kb + 1) * DF + c] = v.y;
            Wsk[(kb + 2) * DF + c] = v.z;
            Wsk[(kb + 3) * DF + c] = v.w;
        }
        __syncthreads();

#pragma unroll
        for (int kk = 0; kk < 8; ++kk) {
            const int kb = (k0 >> 2) + kk;
            float4 w0 = Ws4[(kk * 4 + 0) * 32 + cgrp];
            float4 w1 = Ws4[(kk * 4 + 1) * 32 + cgrp];
            float4 w2 = Ws4[(kk * 4 + 2) * 32 + cgrp];
            float4 w3 = Ws4[(kk * 4 + 3) * 32 + cgrp];
#pragma unroll
            for (int r = 0; r < RPT; ++r) {
                float4 x4 = Xs4[(rgrp * RPT + r) * 32 + kb];
                acc[r].x = fmaf(x4.x, w0.x, acc[r].x);
                acc[r].y = fmaf(x4.x, w0.y, acc[r].y);
                acc[r].z = fmaf(x4.x, w0.z, acc[r].z);
                acc[r].w = fmaf(x4.x, w0.w, acc[r].w);
                acc[r].x = fmaf(x4.y, w1.x, acc[r].x);
                acc[r].y = fmaf(x4.y, w1.y, acc[r].y);
                acc[r].z = fmaf(x4.y, w1.z, acc[r].z);
                acc[r].w = fmaf(x4.y, w1.w, acc[r].w);
                acc[r].x = fmaf(x4.z, w2.x, acc[r].x);
                acc[r].y = fmaf(x4.z, w2.y, acc[r].y);
                acc[r].z = fmaf(x4.z, w2.z, acc[r].z);
                acc[r].w = fmaf(x4.z, w2.w, acc[r].w);
                acc[r].x = fmaf(x4.w, w3.x, acc[r].x);
                acc[r].y = fmaf(x4.w, w3.y, acc[r].y);
                acc[r].z = fmaf(x4.w, w3.z, acc[r].z);
                acc[r].w = fmaf(x4.w, w3.w, acc[r].w);
            }
        }
    }

#pragma unroll
    for (int r = 0; r < RPT; ++r) {
        int n = n0 + rgrp * RPT + r;
        if (n < nrows) {
            if (SCALE_OUT) {
                const float d = rsqrtf(degv[n]);
                acc[r].x *= d; acc[r].y *= d; acc[r].z *= d; acc[r].w *= d;
            }
            ((uint2*)(H + (size_t)n * DF))[cgrp] = f4_to_h4(acc[r]);
        }
    }
}

// ==== fused: blocks [0,gemmBlocks) = GEMM1 64-row tile; rest = CSR build ====
// 64-row tile + 1-edge-per-thread build (R10/R16-measured best).
__global__ __launch_bounds__(256) void build_gemm_kernel(
    const float* __restrict__ X, const float* __restrict__ W,
    const float* __restrict__ b, __half* __restrict__ H, int nrows,
    const int* __restrict__ row, const int* __restrict__ col,
    const float* __restrict__ ew,
    float* __restrict__ deg, int* __restrict__ cnt, int2* __restrict__ csr,
    int E, int gemmBlocks)
{
    __shared__ float Xs[64 * DF];
    __shared__ float Wsk[32 * DF];

    const int tid = threadIdx.x;

    if (blockIdx.x >= gemmBlocks) {
        // ---------------- build part: 1 edge per thread ----------------
        int e = (blockIdx.x - gemmBlocks) * 256 + tid;
        if (e < E) {
            int r = row[e], c = col[e];
            float wv = ew[e];
            atomicAdd(&deg[r], wv);              // fire-and-forget
            int pos = atomicAdd(&cnt[c], 1);     // returning
            if (pos < CAP)
                csr[(size_t)c * CAP + pos] = make_int2(r, __float_as_int(wv));
        }
        return;
    }

    // ---------------- gemm part: stage X tile, then shared GEMM core ----
    const int n0 = blockIdx.x * 64;
#pragma unroll
    for (int i = 0; i < 8; ++i) {
        int idx = tid + i * 256;
        int r   = idx >> 5;
        int kk  = idx & 31;
        int n   = n0 + r;
        float4 v = make_float4(0.f, 0.f, 0.f, 0.f);
        if (n < nrows) v = ((const float4*)(X + (size_t)n * DF))[kk];
        ((float4*)Xs)[idx] = v;
    }
    gemm_from_lds<8, false>(Xs, Wsk, W, b, H, nrows, n0, tid, nullptr);
}

// ==== fused layer boundary: agg1 (+ReLU) -> LDS -> GEMM2, 32-row tile ====
// 32-row tile (32KB LDS) — R15 proved the gather phase needs occupancy.
// Each 32-lane group aggregates its 4 rows as 2 interleaved pairs (agg2).
// Output h2 rows pre-scaled by rsqrt(deg[row]) in the epilogue.
__global__ __launch_bounds__(256) void agg_gemm_kernel(
    const uint2* __restrict__ Hh,       // layer-1 linear output, fp16 rows
    const int2* __restrict__ csr, const int* __restrict__ cnt,
    const float* __restrict__ deg,
    const float* __restrict__ W, const float* __restrict__ b,
    __half* __restrict__ O, int N)
{
    __shared__ float Xs[32 * DF];
    __shared__ float Wsk[32 * DF];

    const int tid = threadIdx.x;
    const int g   = tid >> 5;        // group 0..7, owns rows g*4 .. g*4+3
    const int t   = tid & 31;
    const int n0  = blockIdx.x * 32;

#pragma unroll
    for (int jp = 0; jp < 2; ++jp) {
        const int rA = g * 4 + jp * 2;
        const int rB = rA + 1;
        const int nodeA = n0 + rA;
        const int nodeB = n0 + rB;
        int mA = 0, mB = 0;
        if (nodeA < N) { mA = cnt[nodeA]; if (mA > CAP) mA = CAP; }
        if (nodeB < N) { mB = cnt[nodeB]; if (mB > CAP) mB = CAP; }
        // clamp pointer bases for OOB rows (m=0 -> never dereferenced)
        const int lim = N - 1;
        const int2* bA = csr + (size_t)(nodeA < N ? nodeA : lim) * CAP;
        const int2* bB = csr + (size_t)(nodeB < N ? nodeB : lim) * CAP;
        float4 accA = make_float4(0.f, 0.f, 0.f, 0.f);
        float4 accB = make_float4(0.f, 0.f, 0.f, 0.f);
        agg2<false>(Hh, bA, mA, bB, mB, deg, t, accA, accB);
        if (nodeA < N) {
            const float d = rsqrtf(deg[nodeA]);
            accA.x = fmaxf(accA.x * d, 0.f); accA.y = fmaxf(accA.y * d, 0.f);
            accA.z = fmaxf(accA.z * d, 0.f); accA.w = fmaxf(accA.w * d, 0.f);
        }
        if (nodeB < N) {
            const float d = rsqrtf(deg[nodeB]);
            accB.x = fmaxf(accB.x * d, 0.f); accB.y = fmaxf(accB.y * d, 0.f);
            accB.z = fmaxf(accB.z * d, 0.f); accB.w = fmaxf(accB.w * d, 0.f);
        }
        ((float4*)Xs)[rA * 32 + t] = accA;   // zeros for OOB rows
        ((float4*)Xs)[rB * 32 + t] = accB;
    }
    // (first __syncthreads inside gemm_from_lds's k0 loop fences Xs writes)
    gemm_from_lds<4, true>(Xs, Wsk, W, b, O, N, n0, tid, deg);
}

// ---- final pull aggregation: 2 nodes per half-wave; h2 is pre-scaled fp16 --
__global__ __launch_bounds__(256) void agg_kernel(
    const uint2* __restrict__ Hh,
    const int2* __restrict__ csr, const int* __restrict__ cnt,
    const float* __restrict__ deg,
    float4* __restrict__ O4, int N)
{
    const int gid  = blockIdx.x * blockDim.x + threadIdx.x;
    const int half = gid >> 5;
    const int t    = gid & 31;
    const int nA   = half * 2;
    const int nB   = nA + 1;
    if (nA >= N) return;
    int mA = cnt[nA]; if (mA > CAP) mA = CAP;
    int mB = 0;
    if (nB < N) { mB = cnt[nB]; if (mB > CAP) mB = CAP; }
    const int2* bA = csr + (size_t)nA * CAP;
    const int2* bB = csr + (size_t)(nB < N ? nB : (N - 1)) * CAP;
    float4 accA = make_float4(0.f, 0.f, 0.f, 0.f);
    float4 accB = make_float4(0.f, 0.f, 0.f, 0.f);
    agg2<true>(Hh, bA, mA, bB, mB, deg, t, accA, accB);
    const float dA = rsqrtf(deg[nA]);
    accA.x *= dA; accA.y *= dA; accA.z *= dA; accA.w *= dA;
    O4[(size_t)nA * 32 + t] = accA;
    if (nB < N) {
        const float dB = rsqrtf(deg[nB]);
        accB.x *= dB; accB.y *= dB; accB.z *= dB; accB.w *= dB;
        O4[(size_t)nB * 32 + t] = accB;
    }
}

extern "C" void kernel_launch(void* const* d_in, const int* in_sizes, int n_in,
                              void* d_out, int out_size, void* d_ws, size_t ws_size,
                              hipStream_t stream) {
    const float* x  = (const float*)d_in[0];
    const int*   ei = (const int*)d_in[1];
    const float* ew = (const float*)d_in[2];
    const float* W1 = (const float*)d_in[3];
    const float* b1 = (const float*)d_in[4];
    const float* W2 = (const float*)d_in[5];
    const float* b2 = (const float*)d_in[6];
    float* out = (float*)d_out;

    const int E = in_sizes[2];        // 600000
    const int N = in_sizes[0] / DF;   // 50000
    const int* row = ei;
    const int* col = ei + E;

    char* ws = (char*)d_ws;
    size_t offb = 0;
    auto alloc = [&](size_t bytes) { char* p = ws + offb; offb = (offb + bytes + 511) & ~(size_t)511; return p; };
    float*  deg = (float*)alloc((size_t)2 * N * 4);      // deg | cnt combined (one memset)
    int*    cnt = (int*)(deg + N);
    int2*   csr = (int2*)alloc((size_t)N * CAP * 8);     // packed (src, w) records
    __half* h1  = (__half*)alloc((size_t)N * DF * 2);    // layer-1 linear out (fp16)
    __half* h2  = (__half*)alloc((size_t)N * DF * 2);    // layer-2 linear out (fp16, pre-scaled)
    (void)ws_size;

    hipMemsetAsync(deg, 0, (size_t)2 * N * 4, stream);

    const int TB = 256;
    const int eblocks = (E + TB - 1) / TB;               // 1 edge per thread
    const int gemm1_blocks = (N + 63) / 64;              // 64-row tiles
    const int agg_gemm_blocks = (N + 31) / 32;           // 32-row tiles

    // ---- fused: gemm1 + CSR build ----
    build_gemm_kernel<<<gemm1_blocks + eblocks, 256, 0, stream>>>(
        x, W1, b1, h1, N, row, col, ew, deg, cnt, csr, E, gemm1_blocks);

    // ---- fused: agg1 (+ReLU) -> LDS -> gemm2 (pre-scaled fp16 output) ----
    agg_gemm_kernel<<<agg_gemm_blocks, 256, 0, stream>>>(
        (const uint2*)h1, csr, cnt, deg, W2, b2, h2, N);

    // ---- final aggregation: 2 nodes per half-wave ----
    const int pairs = (N + 1) / 2;
    const int agg_blocks = (pairs * 32 + TB - 1) / TB;
    agg_kernel<<<agg_blocks, TB, 0, stream>>>((const uint2*)h2, csr, cnt, deg,
                                              (float4*)out, N);
}